// Round 17
// baseline (382.332 us; speedup 1.0000x reference)
//
#include <hip/hip_runtime.h>

// KNN top-16: B=4, N=M=8192, C=3.
// 256 threads = 64 queries x 4 subset-threads; each subset-thread scans refs
// with index ≡ h (mod 4), keeps an exact sorted top-16 in registers via an
// LDS candidate buffer with wave-synchronized compaction.
//
// GOLD MODEL (R17):
//   norms : numpy einsum SIMD horizontal sum (baseline SSE2 npyv_sum_f32,
//           movehl+add on zero-padded [x²,y²,z²,0]):
//              n2 = (x² + z²) + y²        [plain muls — HSUM topology]
//   cross : BLAS sgemm => ascending FMA chain fma(z,z', fma(y,y', x*x'))
//   d2    : max((q2 + r2) - 2*cross, 0)
//   sel   : STABLE (d2, idx) ascending, 0-based.
// Locked by 16 probes: combine (others flip S5424), cross (others flip
// S6704), stable ties (R16 anti-stable flipped ~10 tie sites, worst S7351).
// Norm axis: fwd-plain 4848, rev-plain 3714, fwd-FMA 3760, rev-FMA 4848 —
// hsum is the unique untried plain topology.

#define TPB 256
#define QPB 64   // queries per block
#define SPL 4    // threads per query
#define KK 16
#define TILE_PTS 512
#define CAP 32   // LDS candidate slots per thread
#define TRIG 24  // compaction trigger (checked every 8; 24+8 <= 32)

__global__ __launch_bounds__(TPB, 2) void knn_topk_kernel(
    const float* __restrict__ ref, const float* __restrict__ query,
    float* __restrict__ dout, float* __restrict__ iout, int N, int M) {
#pragma clang fp contract(off)
  __shared__ float4 tile[TILE_PTS];              // 8 KB: x,y,z,r2
  __shared__ float sd[CAP * TPB];                // 32 KB: buffered d2
  __shared__ unsigned short si[CAP * TPB];       // 16 KB: buffered ref idx

  const int tid = threadIdx.x;
  const int h = tid & (SPL - 1);
  const int qid = blockIdx.x * QPB + (tid >> 2);
  const int b = qid / M;

  const float* qp = query + (size_t)qid * 3;
  const float qx = qp[0], qy = qp[1], qz = qp[2];
  // HSUM norm (SSE2 movehl reduction of [x2,y2,z2,0]): (x2 + z2) + y2
  float q2 = (qx * qx + qz * qz) + qy * qy;

  float a[KK];
  int ai[KK];
#pragma unroll
  for (int s = 0; s < KK; ++s) { a[s] = 3.0e38f; ai[s] = 0; }
  float T = 3.0e38f;  // = a[15]
  int cnt = 0;

  const float* refb = ref + (size_t)b * N * 3;

  // Insert (d,ix) into sorted-ascending a[]/ai[]; stable (after equals).
  auto insert16 = [&](float d, int ix) {
    bool pc = false;
    float pa = 0.f;
    int pi = 0;
#pragma unroll
    for (int s = 0; s < KK; ++s) {
      float oa = a[s];
      int oi = ai[s];
      bool c = d < oa;  // strict: later-scanned (higher idx) goes after equals
      a[s] = c ? (pc ? pa : d) : oa;
      ai[s] = c ? (pc ? pi : ix) : oi;
      pc = c;
      pa = oa;
      pi = oi;
    }
  };

  auto compact = [&]() {
    int cm = cnt;
    for (int s = 0; s < cm; ++s) {
      float d = sd[s * TPB + tid];
      int ix = si[s * TPB + tid];
      if (d < a[KK - 1]) insert16(d, ix);
    }
    cnt = 0;
    T = a[KK - 1];
  };

  const int ntiles = N / TILE_PTS;
  for (int t = 0; t < ntiles; ++t) {
    __syncthreads();
    {
      // Stage 512 points; r2 = HSUM norm (x2+z2)+y2.
      int pl = tid * 2;
      const float* rp = refb + (size_t)(t * TILE_PTS + pl) * 3;
#pragma unroll
      for (int u = 0; u < 2; ++u) {
        float rx = rp[3 * u + 0];
        float ry = rp[3 * u + 1];
        float rz = rp[3 * u + 2];
        float r2 = (rx * rx + rz * rz) + ry * ry;
        tile[pl + u] = make_float4(rx, ry, rz, r2);
      }
    }
    __syncthreads();
    const int tbase = t * TILE_PTS;
    for (int g = 0; g < TILE_PTS / SPL; g += 8) {
#pragma unroll
      for (int u = 0; u < 8; ++u) {
        const int i = g + u;
        float4 p = tile[i * SPL + h];  // subset h: refs ≡ h (mod 4)
        // cross = ascending-k FMA chain (BLAS sgemm microkernel):
        float cr = qx * p.x;
        cr = __builtin_fmaf(qy, p.y, cr);
        cr = __builtin_fmaf(qz, p.z, cr);
        float s2 = q2 + p.w;           // (q_sq + r_sq), one rounding
        float d2 = s2 - 2.0f * cr;     // - 2*cross (2*cr exact), one rounding
        if (d2 < T) {  // rare after warmup: buffered append
          float d2c = d2 < 0.f ? 0.f : d2;
          sd[cnt * TPB + tid] = d2c;
          si[cnt * TPB + tid] = (unsigned short)(tbase + i * SPL + h);
          cnt++;
        }
      }
      if (__any(cnt >= TRIG)) compact();  // wave-synchronized
    }
  }
  compact();

  // Dump per-thread sorted lists to LDS (reuse buffers), then 4-way merge.
#pragma unroll
  for (int s = 0; s < KK; ++s) {
    sd[s * TPB + tid] = a[s];
    si[s * TPB + tid] = (unsigned short)ai[s];
  }
  __syncthreads();
  if (h == 0) {
    int pp[SPL];
    float hd[SPL];
    int hi[SPL];
#pragma unroll
    for (int j = 0; j < SPL; ++j) {
      pp[j] = 0;
      hd[j] = sd[tid + j];
      hi[j] = si[tid + j];
    }
    float* dq = dout + (size_t)qid * KK;
    float* iq = iout + (size_t)qid * KK;
    for (int o = 0; o < KK; ++o) {
      int best = 0;
#pragma unroll
      for (int j = 1; j < SPL; ++j) {
        bool bt = (hd[j] < hd[best]) || (hd[j] == hd[best] && hi[j] < hi[best]);
        if (bt) best = j;
      }
      dq[o] = sqrtf(hd[best]);
      iq[o] = (float)hi[best];  // 0-based
      int np = pp[best] + 1;
      pp[best] = np;
      if (np < KK) {
        hd[best] = sd[np * TPB + tid + best];
        hi[best] = si[np * TPB + tid + best];
      } else {
        hd[best] = 3.0e38f;
      }
    }
  }
}

extern "C" void kernel_launch(void* const* d_in, const int* in_sizes, int n_in,
                              void* d_out, int out_size, void* d_ws, size_t ws_size,
                              hipStream_t stream) {
  const float* ref = (const float*)d_in[0];
  const float* query = (const float*)d_in[1];
  const int B = 4, C = 3;
  int N = in_sizes[0] / (B * C);
  int M = in_sizes[1] / (B * C);
  float* dout = (float*)d_out;
  float* iout = dout + (size_t)out_size / 2;  // idx half, written as float
  int totalQ = B * M;
  int blocks = totalQ / QPB;
  knn_topk_kernel<<<blocks, TPB, 0, stream>>>(ref, query, dout, iout, N, M);
}

// Round 18
// 333.144 us; speedup vs baseline: 1.1476x; 1.1476x over previous
//
#include <hip/hip_runtime.h>

// KNN top-16: B=4, N=M=8192, C=3.  (GOLD METRIC LOCKED by R17, absmax=0:
//   norms = (x²+z²)+y² [hsum, plain]; cross = fma(z,z',fma(y,y',x*x'));
//   d2 = max((q2+r2) - 2*cross, 0); stable (d2,idx) ascending; 0-based.)
// R18: occupancy attack. 256 threads = 32 queries x 8 subset-threads
// (refs ≡ h mod 8), 1024 blocks (4/CU resident), CAP 32->16 => LDS 56->32KB
// (tile 8K + sd 16K + si 8K). d2 via fmaf(-2,cr,s2): bit-identical to
// s2-2*cr (2*cr exact => both round once), one VALU fewer per point.

#define TPB 256
#define QPB 32   // queries per block
#define SPL 8    // threads per query
#define KK 16
#define TILE_PTS 512
#define CAP 16   // LDS candidate slots per thread
#define TRIG 8   // compaction trigger (checked every 8; 7+8 <= 16)

__global__ __launch_bounds__(TPB, 4) void knn_topk_kernel(
    const float* __restrict__ ref, const float* __restrict__ query,
    float* __restrict__ dout, float* __restrict__ iout, int N, int M) {
#pragma clang fp contract(off)
  __shared__ float4 tile[TILE_PTS];              // 8 KB: x,y,z,r2
  __shared__ float sd[CAP * TPB];                // 16 KB: buffered d2
  __shared__ unsigned short si[CAP * TPB];       // 8 KB: buffered ref idx

  const int tid = threadIdx.x;
  const int h = tid & (SPL - 1);
  const int qid = blockIdx.x * QPB + (tid >> 3);
  const int b = qid / M;

  const float* qp = query + (size_t)qid * 3;
  const float qx = qp[0], qy = qp[1], qz = qp[2];
  // HSUM norm (SSE2 movehl reduction of [x2,y2,z2,0]): (x2 + z2) + y2
  float q2 = (qx * qx + qz * qz) + qy * qy;

  float a[KK];
  int ai[KK];
#pragma unroll
  for (int s = 0; s < KK; ++s) { a[s] = 3.0e38f; ai[s] = 0; }
  float T = 3.0e38f;  // = a[15]
  int cnt = 0;

  const float* refb = ref + (size_t)b * N * 3;

  // Insert (d,ix) into sorted-ascending a[]/ai[]; stable (after equals).
  auto insert16 = [&](float d, int ix) {
    bool pc = false;
    float pa = 0.f;
    int pi = 0;
#pragma unroll
    for (int s = 0; s < KK; ++s) {
      float oa = a[s];
      int oi = ai[s];
      bool c = d < oa;  // strict: later-scanned (higher idx) goes after equals
      a[s] = c ? (pc ? pa : d) : oa;
      ai[s] = c ? (pc ? pi : ix) : oi;
      pc = c;
      pa = oa;
      pi = oi;
    }
  };

  auto compact = [&]() {
    int cm = cnt;
    for (int s = 0; s < cm; ++s) {
      float d = sd[s * TPB + tid];
      int ix = si[s * TPB + tid];
      if (d < a[KK - 1]) insert16(d, ix);
    }
    cnt = 0;
    T = a[KK - 1];
  };

  const int ntiles = N / TILE_PTS;
  for (int t = 0; t < ntiles; ++t) {
    __syncthreads();
    {
      // Stage 512 points; r2 = HSUM norm (x2+z2)+y2.
      int pl = tid * 2;
      const float* rp = refb + (size_t)(t * TILE_PTS + pl) * 3;
#pragma unroll
      for (int u = 0; u < 2; ++u) {
        float rx = rp[3 * u + 0];
        float ry = rp[3 * u + 1];
        float rz = rp[3 * u + 2];
        float r2 = (rx * rx + rz * rz) + ry * ry;
        tile[pl + u] = make_float4(rx, ry, rz, r2);
      }
    }
    __syncthreads();
    const int tbase = t * TILE_PTS;
    for (int g = 0; g < TILE_PTS / SPL; g += 8) {
#pragma unroll
      for (int u = 0; u < 8; ++u) {
        const int i = g + u;
        float4 p = tile[i * SPL + h];  // subset h: refs ≡ h (mod 8)
        // cross = ascending-k FMA chain (BLAS sgemm microkernel):
        float cr = qx * p.x;
        cr = __builtin_fmaf(qy, p.y, cr);
        cr = __builtin_fmaf(qz, p.z, cr);
        float s2 = q2 + p.w;                       // (q2 + r2), one rounding
        float d2 = __builtin_fmaf(-2.0f, cr, s2);  // == round(s2 - 2*cr)
        if (d2 < T) {  // rare after warmup: buffered append
          float d2c = d2 < 0.f ? 0.f : d2;
          sd[cnt * TPB + tid] = d2c;
          si[cnt * TPB + tid] = (unsigned short)(tbase + i * SPL + h);
          cnt++;
        }
      }
      if (__any(cnt >= TRIG)) compact();  // wave-synchronized
    }
  }
  compact();

  // Dump per-thread sorted lists to LDS (reuse buffers), then 8-way merge.
#pragma unroll
  for (int s = 0; s < KK; ++s) {
    sd[s * TPB + tid] = a[s];
    si[s * TPB + tid] = (unsigned short)ai[s];
  }
  __syncthreads();
  if (h == 0) {
    int pp[SPL];
    float hd[SPL];
    int hi[SPL];
#pragma unroll
    for (int j = 0; j < SPL; ++j) {
      pp[j] = 0;
      hd[j] = sd[tid + j];
      hi[j] = si[tid + j];
    }
    float* dq = dout + (size_t)qid * KK;
    float* iq = iout + (size_t)qid * KK;
    for (int o = 0; o < KK; ++o) {
      int best = 0;
#pragma unroll
      for (int j = 1; j < SPL; ++j) {
        bool bt = (hd[j] < hd[best]) || (hd[j] == hd[best] && hi[j] < hi[best]);
        if (bt) best = j;
      }
      dq[o] = sqrtf(hd[best]);
      iq[o] = (float)hi[best];  // 0-based
      int np = pp[best] + 1;
      pp[best] = np;
      if (np < KK) {
        hd[best] = sd[np * TPB + tid + best];
        hi[best] = si[np * TPB + tid + best];
      } else {
        hd[best] = 3.0e38f;
      }
    }
  }
}

extern "C" void kernel_launch(void* const* d_in, const int* in_sizes, int n_in,
                              void* d_out, int out_size, void* d_ws, size_t ws_size,
                              hipStream_t stream) {
  const float* ref = (const float*)d_in[0];
  const float* query = (const float*)d_in[1];
  const int B = 4, C = 3;
  int N = in_sizes[0] / (B * C);
  int M = in_sizes[1] / (B * C);
  float* dout = (float*)d_out;
  float* iout = dout + (size_t)out_size / 2;  // idx half, written as float
  int totalQ = B * M;
  int blocks = totalQ / QPB;
  knn_topk_kernel<<<blocks, TPB, 0, stream>>>(ref, query, dout, iout, N, M);
}

// Round 19
// 286.296 us; speedup vs baseline: 1.3354x; 1.1636x over previous
//
#include <hip/hip_runtime.h>

// KNN top-16: B=4, N=M=8192, C=3.  (GOLD METRIC LOCKED by R17, absmax=0:
//   norms = (x²+z²)+y² [hsum, plain]; cross = fma(z,z',fma(y,y',x*x'));
//   d2 = max((q2+r2) - 2*cross, 0); stable (d2,idx) ascending; 0-based.)
// R19: selection-cost attack (R18 is VALU-issue-bound at 83% busy).
//  - Shared screen threshold per query: T = min over the 8 subset-threads'
//    a[15] (3x shfl_xor+min; global-16th <= min_h per-thread-16th => safe;
//    '<=' keeps exact ties for the exact merge). ~4-8x fewer screen passes,
//    inserts, and compacts than per-thread thresholds.
//  - Appends store ONLY the tile-local idx (ds_write_u16); compact
//    recomputes the bit-identical metric from the live tile (forced
//    compact at tile end). sd[] eliminated.

#define TPB 256
#define QPB 32   // queries per block
#define SPL 8    // threads per query
#define KK 16
#define TILE_PTS 512
#define CAP 16   // LDS candidate slots per thread
#define TRIG 8   // compaction trigger (checked every 8; 7+8 <= 16)

__global__ __launch_bounds__(TPB, 4) void knn_topk_kernel(
    const float* __restrict__ ref, const float* __restrict__ query,
    float* __restrict__ dout, float* __restrict__ iout, int N, int M) {
#pragma clang fp contract(off)
  __shared__ float4 tile[TILE_PTS];              // 8 KB: x,y,z,r2
  __shared__ unsigned short si[CAP * TPB];       // 8 KB: buffered local idx / mi
  __shared__ float md[KK * TPB];                 // 16 KB: merge staging

  const int tid = threadIdx.x;
  const int h = tid & (SPL - 1);
  const int qid = blockIdx.x * QPB + (tid >> 3);
  const int b = qid / M;

  const float* qp = query + (size_t)qid * 3;
  const float qx = qp[0], qy = qp[1], qz = qp[2];
  // HSUM norm (SSE2 movehl reduction of [x2,y2,z2,0]): (x2 + z2) + y2
  float q2 = (qx * qx + qz * qz) + qy * qy;

  float a[KK];
  int ai[KK];
#pragma unroll
  for (int s = 0; s < KK; ++s) { a[s] = 3.0e38f; ai[s] = 0; }
  float T = 3.0e38f;  // shared screen threshold (min of 8 threads' a[15])
  int cnt = 0;

  const float* refb = ref + (size_t)b * N * 3;

  // Insert (d,ix) into sorted-ascending a[]/ai[]; stable (after equals).
  auto insert16 = [&](float d, int ix) {
    bool pc = false;
    float pa = 0.f;
    int pi = 0;
#pragma unroll
    for (int s = 0; s < KK; ++s) {
      float oa = a[s];
      int oi = ai[s];
      bool c = d < oa;  // strict: later-scanned (higher idx) goes after equals
      a[s] = c ? (pc ? pa : d) : oa;
      ai[s] = c ? (pc ? pi : ix) : oi;
      pc = c;
      pa = oa;
      pi = oi;
    }
  };

  // Recompute exact metric from live tile; insert; refresh shared T.
  // Wave-uniform call sites only (uses cross-lane shuffles).
  auto compact = [&](int tbase) {
    int cm = cnt;
    for (int s = 0; s < cm; ++s) {
      int loc = si[s * TPB + tid];
      float4 p = tile[loc];
      float cr = qx * p.x;
      cr = __builtin_fmaf(qy, p.y, cr);
      cr = __builtin_fmaf(qz, p.z, cr);
      float s2 = q2 + p.w;
      float d2 = __builtin_fmaf(-2.0f, cr, s2);
      float d2c = d2 < 0.f ? 0.f : d2;
      if (d2c < a[KK - 1]) insert16(d2c, tbase + loc);
    }
    cnt = 0;
    float a15 = a[KK - 1];
    float m = fminf(a15, __shfl_xor(a15, 1));
    m = fminf(m, __shfl_xor(m, 2));
    T = fminf(m, __shfl_xor(m, 4));
  };

  const int ntiles = N / TILE_PTS;
  for (int t = 0; t < ntiles; ++t) {
    __syncthreads();
    {
      // Stage 512 points; r2 = HSUM norm (x2+z2)+y2.
      int pl = tid * 2;
      const float* rp = refb + (size_t)(t * TILE_PTS + pl) * 3;
#pragma unroll
      for (int u = 0; u < 2; ++u) {
        float rx = rp[3 * u + 0];
        float ry = rp[3 * u + 1];
        float rz = rp[3 * u + 2];
        float r2 = (rx * rx + rz * rz) + ry * ry;
        tile[pl + u] = make_float4(rx, ry, rz, r2);
      }
    }
    __syncthreads();
    const int tbase = t * TILE_PTS;
    for (int g = 0; g < TILE_PTS / SPL; g += 8) {
#pragma unroll
      for (int u = 0; u < 8; ++u) {
        const int loc = (g + u) * SPL + h;  // subset h: refs ≡ h (mod 8)
        float4 p = tile[loc];
        // cross = ascending-k FMA chain (BLAS sgemm microkernel):
        float cr = qx * p.x;
        cr = __builtin_fmaf(qy, p.y, cr);
        cr = __builtin_fmaf(qz, p.z, cr);
        float s2 = q2 + p.w;                       // (q2 + r2), one rounding
        float d2 = __builtin_fmaf(-2.0f, cr, s2);  // == round(s2 - 2*cr)
        if (d2 <= T) {  // conservative shared screen (<= keeps exact ties)
          si[cnt * TPB + tid] = (unsigned short)loc;
          cnt++;
        }
      }
      if (__any(cnt >= TRIG)) compact(tbase);  // wave-synchronized
    }
    if (__any(cnt > 0)) compact(tbase);  // tile retires: resolve local idxs
  }

  // Dump per-thread sorted lists to LDS (si doubles as mi), 8-way merge.
#pragma unroll
  for (int s = 0; s < KK; ++s) {
    md[s * TPB + tid] = a[s];
    si[s * TPB + tid] = (unsigned short)ai[s];
  }
  __syncthreads();
  if (h == 0) {
    int pp[SPL];
    float hd[SPL];
    int hi[SPL];
#pragma unroll
    for (int j = 0; j < SPL; ++j) {
      pp[j] = 0;
      hd[j] = md[tid + j];
      hi[j] = si[tid + j];
    }
    float* dq = dout + (size_t)qid * KK;
    float* iq = iout + (size_t)qid * KK;
    for (int o = 0; o < KK; ++o) {
      int best = 0;
#pragma unroll
      for (int j = 1; j < SPL; ++j) {
        bool bt = (hd[j] < hd[best]) || (hd[j] == hd[best] && hi[j] < hi[best]);
        if (bt) best = j;
      }
      dq[o] = sqrtf(hd[best]);
      iq[o] = (float)hi[best];  // 0-based
      int np = pp[best] + 1;
      pp[best] = np;
      if (np < KK) {
        hd[best] = md[np * TPB + tid + best];
        hi[best] = si[np * TPB + tid + best];
      } else {
        hd[best] = 3.0e38f;
      }
    }
  }
}

extern "C" void kernel_launch(void* const* d_in, const int* in_sizes, int n_in,
                              void* d_out, int out_size, void* d_ws, size_t ws_size,
                              hipStream_t stream) {
  const float* ref = (const float*)d_in[0];
  const float* query = (const float*)d_in[1];
  const int B = 4, C = 3;
  int N = in_sizes[0] / (B * C);
  int M = in_sizes[1] / (B * C);
  float* dout = (float*)d_out;
  float* iout = dout + (size_t)out_size / 2;  // idx half, written as float
  int totalQ = B * M;
  int blocks = totalQ / QPB;
  knn_topk_kernel<<<blocks, TPB, 0, stream>>>(ref, query, dout, iout, N, M);
}